// Round 1
// baseline (335.977 us; speedup 1.0000x reference)
//
#include <hip/hip_runtime.h>

#define NP 8        // poses
#define NB 160      // blocks per pose
#define NA 32       // atoms per block
#define NATYPE 16   // NAT
#define NPOLY 11
#define MIN_SEP 4
#define NPAIRS (NP*NB*NB)   // 204800

__global__ void zero_out_kernel(float* out) {
    if (threadIdx.x < NP) out[threadIdx.x] = 0.0f;
}

__global__ __launch_bounds__(256) void hbond_kernel(
    const float* __restrict__ coords,        // (P, N*A, 3)
    const int*   __restrict__ dispatch,      // (NPAIRS, 3)
    const int*   __restrict__ coord_off,     // (P, N)
    const int*   __restrict__ block_type,    // (P, N)
    const int*   __restrict__ min_sep,       // (P, N, N)
    const int*   __restrict__ n_donH,        // (BT,)
    const int*   __restrict__ n_acc,         // (BT,)
    const int*   __restrict__ donH_inds,     // (BT, 4)
    const int*   __restrict__ acc_inds,      // (BT, 8)
    const int*   __restrict__ donor_type,    // (BT, 4)
    const int*   __restrict__ acceptor_type, // (BT, 8)
    const int*   __restrict__ acceptor_hyb,  // (BT, 8)
    const float* __restrict__ pair_params,   // (256, 3)
    const float* __restrict__ pair_poly,     // (256, 11)
    const float* __restrict__ gp,            // (4,)
    float*       __restrict__ out)           // (P,)
{
    const int gid   = blockIdx.x * 256 + threadIdx.x;
    const int pair  = gid >> 5;          // 32 threads per block-pair
    const int combo = gid & 31;
    const int don   = combo >> 3;        // 0..3
    const int acc   = combo & 7;         // 0..7

    const int p  = dispatch[pair * 3 + 0];
    const int b1 = dispatch[pair * 3 + 1];
    const int b2 = dispatch[pair * 3 + 2];

    float energy = 0.0f;

    const bool pair_ok = (b1 != b2) &&
                         (min_sep[(p * NB + b1) * NB + b2] >= MIN_SEP);
    if (pair_ok) {
        const int bt1 = block_type[p * NB + b1];
        const int bt2 = block_type[p * NB + b2];
        const bool dv = don < n_donH[bt1];
        const bool av = acc < n_acc[bt2];
        if (dv && av) {
            const int off1  = coord_off[p * NB + b1];
            const int off2  = coord_off[p * NB + b2];
            const int hatom = donH_inds[bt1 * 4 + don];
            const int aatom = acc_inds[bt2 * 8 + acc];

            const float* Hc = coords + ((size_t)p * (NB * NA) + off1 + hatom) * 3;
            const float* Ac = coords + ((size_t)p * (NB * NA) + off2 + aatom) * 3;
            const float dx = Hc[0] - Ac[0];
            const float dy = Hc[1] - Ac[1];
            const float dz = Hc[2] - Ac[2];
            const float d  = sqrtf(dx * dx + dy * dy + dz * dz + 1e-12f);

            const int pt = donor_type[bt1 * 4 + don] * NATYPE +
                           acceptor_type[bt2 * 8 + acc];

            const float* c = pair_poly + pt * NPOLY;
            float e = c[0];
            #pragma unroll
            for (int k = 1; k < NPOLY; ++k) e = e * d + c[k];

            const int   hyb = acceptor_hyb[bt2 * 8 + acc];
            const float w   = pair_params[pt * 3 + hyb];

            e = fmaxf(fminf(e, 0.0f), gp[1]);
            if (d < gp[0]) energy = w * e;
        }
    }

    // Wave-64 reduction
    #pragma unroll
    for (int off = 32; off >= 1; off >>= 1)
        energy += __shfl_down(energy, off, 64);

    __shared__ float lds[4];
    const int wave = threadIdx.x >> 6;
    const int lane = threadIdx.x & 63;
    if (lane == 0) lds[wave] = energy;
    __syncthreads();

    // All 8 pairs in this block share the same pose p
    // (25600 pairs per pose, 8 pairs per block, 25600 % 8 == 0).
    if (threadIdx.x == 0) {
        const float s = lds[0] + lds[1] + lds[2] + lds[3];
        atomicAdd(out + p, s);
    }
}

extern "C" void kernel_launch(void* const* d_in, const int* in_sizes, int n_in,
                              void* d_out, int out_size, void* d_ws, size_t ws_size,
                              hipStream_t stream) {
    const float* coords        = (const float*)d_in[0];
    const int*   dispatch      = (const int*)  d_in[1];
    const int*   coord_off     = (const int*)  d_in[2];
    const int*   block_type    = (const int*)  d_in[3];
    const int*   min_sep       = (const int*)  d_in[4];
    const int*   n_donH        = (const int*)  d_in[5];
    const int*   n_acc         = (const int*)  d_in[6];
    const int*   donH_inds     = (const int*)  d_in[7];
    const int*   acc_inds      = (const int*)  d_in[8];
    const int*   donor_type    = (const int*)  d_in[9];
    const int*   acceptor_type = (const int*)  d_in[10];
    const int*   acceptor_hyb  = (const int*)  d_in[11];
    const float* pair_params   = (const float*)d_in[12];
    const float* pair_poly     = (const float*)d_in[13];
    const float* gp            = (const float*)d_in[14];
    float*       out           = (float*)d_out;

    zero_out_kernel<<<1, 64, 0, stream>>>(out);

    const int total_threads = NPAIRS * 32;          // 6,553,600
    const int blocks        = total_threads / 256;  // 25,600
    hbond_kernel<<<blocks, 256, 0, stream>>>(
        coords, dispatch, coord_off, block_type, min_sep,
        n_donH, n_acc, donH_inds, acc_inds,
        donor_type, acceptor_type, acceptor_hyb,
        pair_params, pair_poly, gp, out);
}

// Round 2
// 35.055 us; speedup vs baseline: 9.5844x; 9.5844x over previous
//
#include <hip/hip_runtime.h>

#define NP 8        // poses
#define NB 160      // blocks per pose
#define NA 32       // atoms per block
#define NATYPE 16   // NAT
#define NPOLY 11
#define MIN_SEP 4
#define NPT 256     // ND*NAT pair types

__global__ void zero_out_kernel(float* out) {
    if (threadIdx.x < NP) out[threadIdx.x] = 0.0f;
}

// One workgroup per (pose, b1). Stage pose-wide acceptor data + tables in
// LDS once, compact valid b2 list, then each thread owns a fixed (don, acc)
// and strides over valid b2's.
__global__ __launch_bounds__(256, 4) void hbond_kernel(
    const float* __restrict__ coords,        // (P, N*A, 3)
    const int*   __restrict__ coord_off,     // (P, N)
    const int*   __restrict__ block_type,    // (P, N)
    const int*   __restrict__ min_sep,       // (P, N, N)
    const int*   __restrict__ n_donH,        // (BT,)
    const int*   __restrict__ n_acc,         // (BT,)
    const int*   __restrict__ donH_inds,     // (BT, 4)
    const int*   __restrict__ acc_inds,      // (BT, 8)
    const int*   __restrict__ donor_type,    // (BT, 4)
    const int*   __restrict__ acceptor_type, // (BT, 8)
    const int*   __restrict__ acceptor_hyb,  // (BT, 8)
    const float* __restrict__ pair_params,   // (256, 3)
    const float* __restrict__ pair_poly,     // (256, 11)
    const float* __restrict__ gp,            // (4,)
    float*       __restrict__ out)           // (P,)
{
    const int t  = threadIdx.x;
    const int p  = blockIdx.x / NB;
    const int b1 = blockIdx.x % NB;

    __shared__ float4 accd[NB * 8];          // 20480 B: x,y,z, bits(atype|hyb<<4|valid<<8)
    __shared__ float  polyl[NPT * NPOLY];    // 11264 B
    __shared__ float  paraml[NPT * 3];       //  3072 B
    __shared__ int4   b2info[NB];            //  2560 B: (bt2, off2, n_acc, ok)
    __shared__ int    b2list[NB];            //   640 B
    __shared__ float4 dond[4];               // donor: x,y,z, bits(dtype|valid<<8)
    __shared__ int    cnt;
    __shared__ float  wsum[4];

    if (t == 0) cnt = 0;

    // Stage tables (coalesced).
    for (int i = t; i < NPT * NPOLY; i += 256) polyl[i]  = pair_poly[i];
    for (int i = t; i < NPT * 3;     i += 256) paraml[i] = pair_params[i];

    // Per-b2 metadata + pair_ok.
    if (t < NB) {
        const int bt2  = block_type[p * NB + t];
        const int off2 = coord_off[p * NB + t];
        const int na   = n_acc[bt2];
        const int sep  = min_sep[(p * NB + b1) * NB + t];
        const int ok   = (t != b1) && (sep >= MIN_SEP);
        b2info[t] = make_int4(bt2, off2, na, ok);
    }

    // Donor data for b1.
    if (t < 4) {
        const int bt1   = block_type[p * NB + b1];
        const int off1  = coord_off[p * NB + b1];
        const int nd    = n_donH[bt1];
        const int hatom = donH_inds[bt1 * 4 + t];
        const int dtype = donor_type[bt1 * 4 + t];
        const int dval  = (t < nd) ? 1 : 0;
        const float* Hc = coords + (size_t)(p * (NB * NA) + off1 + hatom) * 3;
        float4 v;
        v.x = Hc[0]; v.y = Hc[1]; v.z = Hc[2];
        v.w = __int_as_float((dtype & 0xff) | (dval << 8));
        dond[t] = v;
    }

    __syncthreads();

    // Acceptor staging for the whole pose (reads b2info).
    for (int e = t; e < NB * 8; e += 256) {
        const int b2 = e >> 3;
        const int a  = e & 7;
        const int4 info = b2info[b2];
        float4 v; v.x = 0.0f; v.y = 0.0f; v.z = 0.0f;
        int bits = 0;
        if (a < info.z) {
            const int aidx  = acc_inds[info.x * 8 + a];
            const int atype = acceptor_type[info.x * 8 + a];
            const int hyb   = acceptor_hyb[info.x * 8 + a];
            const float* Ac = coords + (size_t)(p * (NB * NA) + info.y + aidx) * 3;
            v.x = Ac[0]; v.y = Ac[1]; v.z = Ac[2];
            bits = (atype & 0xf) | ((hyb & 3) << 4) | (1 << 8);
        }
        v.w = __int_as_float(bits);
        accd[e] = v;
    }

    // Compact valid b2 (order irrelevant for a sum).
    if (t < NB && b2info[t].w) {
        const int pos = atomicAdd(&cnt, 1);
        b2list[pos] = t;
    }

    __syncthreads();

    // Main loop: thread owns fixed (don, acc), strides over valid b2.
    const int don   = (t >> 3) & 3;
    const int acc   = t & 7;
    const int phase = t >> 5;                 // 0..7

    const float4 dv   = dond[don];
    const int    dbits = __float_as_int(dv.w);
    const float  cut  = gp[0];
    const float  emin = gp[1];

    float energy = 0.0f;
    const int n = cnt;
    if (dbits & 0x100) {
        const int dbase = (dbits & 0xff) * NATYPE;
        for (int i = phase; i < n; i += 8) {
            const int b2 = b2list[i];
            const float4 av = accd[b2 * 8 + acc];
            const int abits = __float_as_int(av.w);
            if (!(abits & 0x100)) continue;
            const float dx = dv.x - av.x;
            const float dy = dv.y - av.y;
            const float dz = dv.z - av.z;
            const float d  = sqrtf(dx * dx + dy * dy + dz * dz + 1e-12f);
            const int pt = dbase + (abits & 0xf);
            const float* c = &polyl[pt * NPOLY];
            float e = c[0];
            #pragma unroll
            for (int k = 1; k < NPOLY; ++k) e = e * d + c[k];
            const float w = paraml[pt * 3 + ((abits >> 4) & 3)];
            e = fmaxf(fminf(e, 0.0f), emin);
            if (d < cut) energy += w * e;
        }
    }

    // Reduce 256 threads -> 1 atomic per workgroup.
    #pragma unroll
    for (int off = 32; off >= 1; off >>= 1)
        energy += __shfl_down(energy, off, 64);
    const int wave = t >> 6, lane = t & 63;
    if (lane == 0) wsum[wave] = energy;
    __syncthreads();
    if (t == 0) atomicAdd(out + p, wsum[0] + wsum[1] + wsum[2] + wsum[3]);
}

extern "C" void kernel_launch(void* const* d_in, const int* in_sizes, int n_in,
                              void* d_out, int out_size, void* d_ws, size_t ws_size,
                              hipStream_t stream) {
    const float* coords        = (const float*)d_in[0];
    // d_in[1] (dispatch) is the full meshgrid (p, b1, b2) — derived from blockIdx instead.
    const int*   coord_off     = (const int*)  d_in[2];
    const int*   block_type    = (const int*)  d_in[3];
    const int*   min_sep       = (const int*)  d_in[4];
    const int*   n_donH        = (const int*)  d_in[5];
    const int*   n_acc         = (const int*)  d_in[6];
    const int*   donH_inds     = (const int*)  d_in[7];
    const int*   acc_inds      = (const int*)  d_in[8];
    const int*   donor_type    = (const int*)  d_in[9];
    const int*   acceptor_type = (const int*)  d_in[10];
    const int*   acceptor_hyb  = (const int*)  d_in[11];
    const float* pair_params   = (const float*)d_in[12];
    const float* pair_poly     = (const float*)d_in[13];
    const float* gp            = (const float*)d_in[14];
    float*       out           = (float*)d_out;

    zero_out_kernel<<<1, 64, 0, stream>>>(out);

    hbond_kernel<<<NP * NB, 256, 0, stream>>>(
        coords, coord_off, block_type, min_sep,
        n_donH, n_acc, donH_inds, acc_inds,
        donor_type, acceptor_type, acceptor_hyb,
        pair_params, pair_poly, gp, out);
}

// Round 3
// 25.768 us; speedup vs baseline: 13.0384x; 1.3604x over previous
//
#include <hip/hip_runtime.h>

#define NP 8        // poses
#define NB 160      // blocks per pose
#define NA 32       // atoms per block
#define NATYPE 16
#define NPOLY 11
#define MIN_SEP 4
#define NPT 256     // pair types
#define PSTRIDE 12  // padded poly row (11 coeffs + 1 pad), 48B -> 16B aligned
#define NBT 2       // b1 blocks per workgroup

__global__ void zero_out_kernel(float* out) {
    if (threadIdx.x < NP) out[threadIdx.x] = 0.0f;
}

__device__ __forceinline__ float pair_loop(
    int phase, int n, const int* __restrict__ list,
    const float4* __restrict__ accd,
    const float* __restrict__ polyl, const float* __restrict__ paraml,
    float hx, float hy, float hz, int dbase,
    float cut, float emin, int acc)
{
    float energy = 0.0f;
    #pragma unroll 2
    for (int i = phase; i < n; i += 8) {
        const int b2 = list[i];
        const float4 av = accd[b2 * 8 + acc];
        const int abits = __float_as_int(av.w);
        const float dx = hx - av.x, dy = hy - av.y, dz = hz - av.z;
        const float d  = sqrtf(dx * dx + dy * dy + dz * dz + 1e-12f);
        const int pt = dbase + (abits & 0xf);
        const float4 c0 = *(const float4*)&polyl[pt * PSTRIDE + 0];
        const float4 c1 = *(const float4*)&polyl[pt * PSTRIDE + 4];
        const float4 c2 = *(const float4*)&polyl[pt * PSTRIDE + 8];
        float e = c0.x;
        e = e * d + c0.y; e = e * d + c0.z; e = e * d + c0.w;
        e = e * d + c1.x; e = e * d + c1.y; e = e * d + c1.z; e = e * d + c1.w;
        e = e * d + c2.x; e = e * d + c2.y; e = e * d + c2.z;
        const float w = paraml[pt * 3 + ((abits >> 4) & 3)];
        e = fmaxf(fminf(e, 0.0f), emin);
        if (d < cut) energy += w * e;
    }
    return energy;
}

// One workgroup per (pose, pair of b1). Pose-wide acceptor data + tables
// staged once per wg; two compact b2 lists built by ballot-scan; each thread
// owns a fixed (don, acc) and phase-strides over valid b2.
__global__ __launch_bounds__(256, 4) void hbond_kernel(
    const float* __restrict__ coords,        // (P, N*A, 3)
    const int*   __restrict__ coord_off,     // (P, N)
    const int*   __restrict__ block_type,    // (P, N)
    const int*   __restrict__ min_sep,       // (P, N, N)
    const int*   __restrict__ n_donH,        // (BT,)
    const int*   __restrict__ n_acc,         // (BT,)
    const int*   __restrict__ donH_inds,     // (BT, 4)
    const int*   __restrict__ acc_inds,      // (BT, 8)
    const int*   __restrict__ donor_type,    // (BT, 4)
    const int*   __restrict__ acceptor_type, // (BT, 8)
    const int*   __restrict__ acceptor_hyb,  // (BT, 8)
    const float* __restrict__ pair_params,   // (256, 3)
    const float* __restrict__ pair_poly,     // (256, 11)
    const float* __restrict__ gp,            // (4,)
    float*       __restrict__ out)           // (P,)
{
    const int t  = threadIdx.x;
    const int p  = blockIdx.x / (NB / NBT);
    const int pr = blockIdx.x % (NB / NBT);
    const int b1a = pr * NBT;
    const int b1b = b1a + 1;

    __shared__ __align__(16) float4 accd[NB * 8];        // 20480 B
    __shared__ __align__(16) float  polyl[NPT * PSTRIDE];// 12288 B
    __shared__ float  paraml[NPT * 3];                   //  3072 B
    __shared__ int    b2listA[NB];                       //   640 B
    __shared__ int    b2listB[NB];                       //   640 B
    __shared__ int    wcntA[3], wcntB[3];
    __shared__ float  wsum[4];

    // ---- donor prefetch for both b1 (register-resident, scalar-path) ----
    const int don = (t >> 3) & 3;
    const int acc = t & 7;

    const int bt1a = block_type[p * NB + b1a];
    const int bt1b = block_type[p * NB + b1b];
    const int off1a = coord_off[p * NB + b1a];
    const int off1b = coord_off[p * NB + b1b];
    const bool dvA = don < n_donH[bt1a];
    const bool dvB = don < n_donH[bt1b];
    const int hatomA = donH_inds[bt1a * 4 + don];
    const int hatomB = donH_inds[bt1b * 4 + don];
    const int dbaseA = donor_type[bt1a * 4 + don] * NATYPE;
    const int dbaseB = donor_type[bt1b * 4 + don] * NATYPE;
    const float* HcA = coords + (size_t)(p * (NB * NA) + off1a + hatomA) * 3;
    const float* HcB = coords + (size_t)(p * (NB * NA) + off1b + hatomB) * 3;
    const float hxA = HcA[0], hyA = HcA[1], hzA = HcA[2];
    const float hxB = HcB[0], hyB = HcB[1], hzB = HcB[2];

    const float cut  = gp[0];
    const float emin = gp[1];

    // ---- stage tables (padded poly, stride 12) ----
    for (int i = t; i < NPT * PSTRIDE; i += 256) {
        const int r = i / PSTRIDE, c = i - r * PSTRIDE;
        polyl[i] = (c < NPOLY) ? pair_poly[r * NPOLY + c] : 0.0f;
    }
    for (int i = t; i < NPT * 3; i += 256) paraml[i] = pair_params[i];

    // ---- stage pose-wide acceptor data (invalid -> poisoned coords) ----
    for (int e = t; e < NB * 8; e += 256) {
        const int b2  = e >> 3;
        const int a   = e & 7;
        const int bt2 = block_type[p * NB + b2];
        float4 v;
        if (a < n_acc[bt2]) {
            const int off2  = coord_off[p * NB + b2];
            const int aidx  = acc_inds[bt2 * 8 + a];
            const int atype = acceptor_type[bt2 * 8 + a];
            const int hyb   = acceptor_hyb[bt2 * 8 + a];
            const float* Ac = coords + (size_t)(p * (NB * NA) + off2 + aidx) * 3;
            v.x = Ac[0]; v.y = Ac[1]; v.z = Ac[2];
            v.w = __int_as_float((atype & 0xf) | ((hyb & 3) << 4));
        } else {
            v.x = 1e9f; v.y = 0.0f; v.z = 0.0f;   // d >= cutoff -> never added
            v.w = __int_as_float(0);
        }
        accd[e] = v;
    }

    // ---- pair_ok ballots for both b1 (no atomics) ----
    bool okA = false, okB = false;
    if (t < NB) {
        okA = (t != b1a) && (min_sep[(p * NB + b1a) * NB + t] >= MIN_SEP);
        okB = (t != b1b) && (min_sep[(p * NB + b1b) * NB + t] >= MIN_SEP);
    }
    const unsigned long long mA = __ballot(okA);
    const unsigned long long mB = __ballot(okB);
    const int wv = t >> 6, ln = t & 63;
    if (ln == 0 && wv < 3) { wcntA[wv] = __popcll(mA); wcntB[wv] = __popcll(mB); }

    __syncthreads();

    int preA = 0, preB = 0, cntA = 0, cntB = 0;
    #pragma unroll
    for (int w = 0; w < 3; ++w) {
        cntA += wcntA[w]; cntB += wcntB[w];
        if (w < wv) { preA += wcntA[w]; preB += wcntB[w]; }
    }
    const unsigned long long below = (1ull << ln) - 1ull;
    if (okA) b2listA[preA + __popcll(mA & below)] = t;
    if (okB) b2listB[preB + __popcll(mB & below)] = t;

    __syncthreads();

    // ---- main loops ----
    const int phase = t >> 5;   // 0..7
    float energy = 0.0f;
    if (dvA) energy += pair_loop(phase, cntA, b2listA, accd, polyl, paraml,
                                 hxA, hyA, hzA, dbaseA, cut, emin, acc);
    if (dvB) energy += pair_loop(phase, cntB, b2listB, accd, polyl, paraml,
                                 hxB, hyB, hzB, dbaseB, cut, emin, acc);

    // ---- reduce 256 threads -> 1 atomic ----
    #pragma unroll
    for (int off = 32; off >= 1; off >>= 1)
        energy += __shfl_down(energy, off, 64);
    if (ln == 0) wsum[wv] = energy;
    __syncthreads();
    if (t == 0) atomicAdd(out + p, wsum[0] + wsum[1] + wsum[2] + wsum[3]);
}

extern "C" void kernel_launch(void* const* d_in, const int* in_sizes, int n_in,
                              void* d_out, int out_size, void* d_ws, size_t ws_size,
                              hipStream_t stream) {
    const float* coords        = (const float*)d_in[0];
    // d_in[1] (dispatch) is the full (p, b1, b2) meshgrid — derived from blockIdx.
    const int*   coord_off     = (const int*)  d_in[2];
    const int*   block_type    = (const int*)  d_in[3];
    const int*   min_sep       = (const int*)  d_in[4];
    const int*   n_donH        = (const int*)  d_in[5];
    const int*   n_acc         = (const int*)  d_in[6];
    const int*   donH_inds     = (const int*)  d_in[7];
    const int*   acc_inds      = (const int*)  d_in[8];
    const int*   donor_type    = (const int*)  d_in[9];
    const int*   acceptor_type = (const int*)  d_in[10];
    const int*   acceptor_hyb  = (const int*)  d_in[11];
    const float* pair_params   = (const float*)d_in[12];
    const float* pair_poly     = (const float*)d_in[13];
    const float* gp            = (const float*)d_in[14];
    float*       out           = (float*)d_out;

    zero_out_kernel<<<1, 64, 0, stream>>>(out);

    hbond_kernel<<<NP * (NB / NBT), 256, 0, stream>>>(
        coords, coord_off, block_type, min_sep,
        n_donH, n_acc, donH_inds, acc_inds,
        donor_type, acceptor_type, acceptor_hyb,
        pair_params, pair_poly, gp, out);
}

// Round 4
// 24.976 us; speedup vs baseline: 13.4520x; 1.0317x over previous
//
#include <hip/hip_runtime.h>

#define NP 8
#define NB 160
#define NA 32
#define NATYPE 16
#define NPOLY 11
#define MIN_SEP 4
#define NPT 256
#define PSTRIDE 12              // padded poly row (11 + 1), 48B, 16B-aligned
#define NBT 2                   // b1 blocks per workgroup
#define NWG_PER_POSE (NB/NBT)   // 80
#define ACC_SLOTS (NB*8)        // 1280
#define DON_SLOTS (NB*4)        // 640
#define WS_DON_OFF (NP*ACC_SLOTS)                  // float4 units
#define WS_NEEDED ((size_t)(NP*(ACC_SLOTS+DON_SLOTS))*16)  // 245760 B
#define AVALID (1<<8)
#define DVALID (1<<16)

__global__ void zero_out_kernel(float* out) {
    if (threadIdx.x < NP) out[threadIdx.x] = 0.0f;
}

// Precompute pose-wide acceptor + donor float4 tables into ws, and zero out.
__global__ __launch_bounds__(256) void pre_kernel(
    const float* __restrict__ coords, const int* __restrict__ coord_off,
    const int* __restrict__ block_type, const int* __restrict__ n_donH,
    const int* __restrict__ n_acc, const int* __restrict__ donH_inds,
    const int* __restrict__ acc_inds, const int* __restrict__ donor_type,
    const int* __restrict__ acceptor_type, const int* __restrict__ acceptor_hyb,
    float4* __restrict__ ws, float* __restrict__ out)
{
    const int gid = blockIdx.x * 256 + threadIdx.x;
    if (gid < NP) out[gid] = 0.0f;
    if (gid < NP * ACC_SLOTS) {
        const int p = gid / ACC_SLOTS, rem = gid % ACC_SLOTS;
        const int b2 = rem >> 3, a = rem & 7;
        const int bt2 = block_type[p * NB + b2];
        float4 v; int bits = 0;
        if (a < n_acc[bt2]) {
            const int off2  = coord_off[p * NB + b2];
            const int aidx  = acc_inds[bt2 * 8 + a];
            const int atype = acceptor_type[bt2 * 8 + a];
            const int hyb   = acceptor_hyb[bt2 * 8 + a];
            const float* Ac = coords + (size_t)(p * (NB * NA) + off2 + aidx) * 3;
            v.x = Ac[0]; v.y = Ac[1]; v.z = Ac[2];
            bits = (atype & 0xf) | ((hyb & 3) << 4) | AVALID;
        } else { v.x = 1e9f; v.y = 0.0f; v.z = 0.0f; }
        v.w = __int_as_float(bits);
        ws[gid] = v;
    }
    if (gid < NP * DON_SLOTS) {
        const int p = gid / DON_SLOTS, rem = gid % DON_SLOTS;
        const int b1 = rem >> 2, don = rem & 3;
        const int bt1   = block_type[p * NB + b1];
        const int off1  = coord_off[p * NB + b1];
        const int hatom = donH_inds[bt1 * 4 + don];
        const int dbase = donor_type[bt1 * 4 + don] * NATYPE;
        const float* Hc = coords + (size_t)(p * (NB * NA) + off1 + hatom) * 3;
        float4 v;
        v.x = Hc[0]; v.y = Hc[1]; v.z = Hc[2];
        v.w = __int_as_float((dbase & 0xff) | ((don < n_donH[bt1]) ? DVALID : 0));
        ws[WS_DON_OFF + gid] = v;
    }
}

__device__ __forceinline__ float seg_loop(
    int t, int cnt, const unsigned short* __restrict__ items,
    const float4* __restrict__ accd,
    const float* __restrict__ polyl, const float* __restrict__ paraml,
    const float4 dv[4], float cut, float emin)
{
    float energy = 0.0f;
    for (int i = t; i < cnt; i += 256) {
        const int e = items[i];
        const float4 av = accd[e];
        const int abits = __float_as_int(av.w);
        const int atype = abits & 0xf;
        const int hyb   = (abits >> 4) & 3;
        #pragma unroll
        for (int dn = 0; dn < 4; ++dn) {
            const int dbits = __float_as_int(dv[dn].w);
            if (dbits & DVALID) {   // wave-uniform (prefix validity per b1)
                const float dx = dv[dn].x - av.x;
                const float dy = dv[dn].y - av.y;
                const float dz = dv[dn].z - av.z;
                const float d  = sqrtf(dx * dx + dy * dy + dz * dz + 1e-12f);
                const int pt = (dbits & 0xff) + atype;
                const float4 c0 = *(const float4*)&polyl[pt * PSTRIDE + 0];
                const float4 c1 = *(const float4*)&polyl[pt * PSTRIDE + 4];
                const float4 c2 = *(const float4*)&polyl[pt * PSTRIDE + 8];
                float ev = c0.x;
                ev = ev * d + c0.y; ev = ev * d + c0.z; ev = ev * d + c0.w;
                ev = ev * d + c1.x; ev = ev * d + c1.y; ev = ev * d + c1.z; ev = ev * d + c1.w;
                ev = ev * d + c2.x; ev = ev * d + c2.y; ev = ev * d + c2.z;
                const float w = paraml[pt * 3 + hyb];
                ev = fmaxf(fminf(ev, 0.0f), emin);
                if (d < cut) energy += w * ev;
            }
        }
    }
    return energy;
}

__global__ __launch_bounds__(256, 3) void hbond_kernel(
    const float* __restrict__ coords,
    const int*   __restrict__ coord_off,
    const int*   __restrict__ block_type,
    const int*   __restrict__ min_sep,
    const int*   __restrict__ n_donH,
    const int*   __restrict__ n_acc,
    const int*   __restrict__ donH_inds,
    const int*   __restrict__ acc_inds,
    const int*   __restrict__ donor_type,
    const int*   __restrict__ acceptor_type,
    const int*   __restrict__ acceptor_hyb,
    const float* __restrict__ pair_params,
    const float* __restrict__ pair_poly,
    const float* __restrict__ gp,
    const float4* __restrict__ ws,
    int pre,
    float*       __restrict__ out)
{
    const int t  = threadIdx.x;
    const int p  = blockIdx.x / NWG_PER_POSE;
    const int pr = blockIdx.x % NWG_PER_POSE;
    const int b1a = pr * NBT, b1b = b1a + 1;

    __shared__ __align__(16) float4 accd[ACC_SLOTS];      // 20480
    __shared__ __align__(16) float  polyl[NPT * PSTRIDE]; // 12288
    __shared__ float  paraml[NPT * 3];                    //  3072
    __shared__ unsigned short itemsA[ACC_SLOTS];          //  2560
    __shared__ unsigned short itemsB[ACC_SLOTS];          //  2560
    __shared__ unsigned char okA[NB], okB[NB];            //   320
    __shared__ int  wcA[5][4], wcB[5][4];                 //   160
    __shared__ float wsum[4];

    // ---- tables ----
    for (int i = t; i < NPT * PSTRIDE; i += 256) {
        const int r = i / PSTRIDE, c = i - r * PSTRIDE;
        polyl[i] = (c < NPOLY) ? pair_poly[r * NPOLY + c] : 0.0f;
    }
    for (int i = t; i < NPT * 3; i += 256) paraml[i] = pair_params[i];

    // ---- acceptor staging ----
    if (pre) {
        const float4* src = ws + p * ACC_SLOTS;
        for (int e = t; e < ACC_SLOTS; e += 256) accd[e] = src[e];
    } else {
        for (int e = t; e < ACC_SLOTS; e += 256) {
            const int b2 = e >> 3, a = e & 7;
            const int bt2 = block_type[p * NB + b2];
            float4 v; int bits = 0;
            if (a < n_acc[bt2]) {
                const int off2  = coord_off[p * NB + b2];
                const int aidx  = acc_inds[bt2 * 8 + a];
                const int atype = acceptor_type[bt2 * 8 + a];
                const int hyb   = acceptor_hyb[bt2 * 8 + a];
                const float* Ac = coords + (size_t)(p * (NB * NA) + off2 + aidx) * 3;
                v.x = Ac[0]; v.y = Ac[1]; v.z = Ac[2];
                bits = (atype & 0xf) | ((hyb & 3) << 4) | AVALID;
            } else { v.x = 1e9f; v.y = 0.0f; v.z = 0.0f; }
            v.w = __int_as_float(bits);
            accd[e] = v;
        }
    }

    // ---- donors -> registers (uniform addresses, broadcast loads) ----
    float4 dA[4], dB[4];
    if (pre) {
        const float4* dsrc = ws + WS_DON_OFF + p * DON_SLOTS;
        #pragma unroll
        for (int dn = 0; dn < 4; ++dn) {
            dA[dn] = dsrc[b1a * 4 + dn];
            dB[dn] = dsrc[b1b * 4 + dn];
        }
    } else {
        const int bt1a = block_type[p * NB + b1a], bt1b = block_type[p * NB + b1b];
        const int off1a = coord_off[p * NB + b1a], off1b = coord_off[p * NB + b1b];
        const int nda = n_donH[bt1a], ndb = n_donH[bt1b];
        #pragma unroll
        for (int dn = 0; dn < 4; ++dn) {
            const float* Ha = coords + (size_t)(p * (NB * NA) + off1a + donH_inds[bt1a * 4 + dn]) * 3;
            const float* Hb = coords + (size_t)(p * (NB * NA) + off1b + donH_inds[bt1b * 4 + dn]) * 3;
            dA[dn] = make_float4(Ha[0], Ha[1], Ha[2], __int_as_float(((donor_type[bt1a * 4 + dn] * NATYPE) & 0xff) | ((dn < nda) ? DVALID : 0)));
            dB[dn] = make_float4(Hb[0], Hb[1], Hb[2], __int_as_float(((donor_type[bt1b * 4 + dn] * NATYPE) & 0xff) | ((dn < ndb) ? DVALID : 0)));
        }
    }

    // ---- pair_ok flags ----
    if (t < NB) {
        okA[t] = (t != b1a) && (min_sep[(p * NB + b1a) * NB + t] >= MIN_SEP);
        okB[t] = (t != b1b) && (min_sep[(p * NB + b1b) * NB + t] >= MIN_SEP);
    }

    __syncthreads();

    // ---- build compacted item lists (valid (b2,acc) slots) ----
    unsigned long long mA[5], mB[5];
    #pragma unroll
    for (int r = 0; r < 5; ++r) {
        const int e  = r * 256 + t;
        const int b2 = e >> 3;
        const int av = __float_as_int(accd[e].w) & AVALID;
        mA[r] = __ballot(okA[b2] && av);
        mB[r] = __ballot(okB[b2] && av);
    }
    const int wv = t >> 6, ln = t & 63;
    if (ln == 0) {
        #pragma unroll
        for (int r = 0; r < 5; ++r) { wcA[r][wv] = __popcll(mA[r]); wcB[r][wv] = __popcll(mB[r]); }
    }
    __syncthreads();

    int cntA = 0, cntB = 0;
    {
        const unsigned long long below = (1ull << ln) - 1ull;
        int baseA = 0, baseB = 0;
        #pragma unroll
        for (int r = 0; r < 5; ++r) {
            int preA = baseA, preB = baseB;
            #pragma unroll
            for (int w = 0; w < 4; ++w) {
                if (w < wv) { preA += wcA[r][w]; preB += wcB[r][w]; }
                baseA += wcA[r][w]; baseB += wcB[r][w];
            }
            if ((mA[r] >> ln) & 1) itemsA[preA + __popcll(mA[r] & below)] = (unsigned short)(r * 256 + t);
            if ((mB[r] >> ln) & 1) itemsB[preB + __popcll(mB[r] & below)] = (unsigned short)(r * 256 + t);
        }
        cntA = baseA; cntB = baseB;
    }
    __syncthreads();

    // ---- main loops ----
    const float cut = gp[0], emin = gp[1];
    float energy = 0.0f;
    energy += seg_loop(t, cntA, itemsA, accd, polyl, paraml, dA, cut, emin);
    energy += seg_loop(t, cntB, itemsB, accd, polyl, paraml, dB, cut, emin);

    // ---- reduce ----
    #pragma unroll
    for (int off = 32; off >= 1; off >>= 1)
        energy += __shfl_down(energy, off, 64);
    if (ln == 0) wsum[wv] = energy;
    __syncthreads();
    if (t == 0) atomicAdd(out + p, wsum[0] + wsum[1] + wsum[2] + wsum[3]);
}

extern "C" void kernel_launch(void* const* d_in, const int* in_sizes, int n_in,
                              void* d_out, int out_size, void* d_ws, size_t ws_size,
                              hipStream_t stream) {
    const float* coords        = (const float*)d_in[0];
    const int*   coord_off     = (const int*)  d_in[2];
    const int*   block_type    = (const int*)  d_in[3];
    const int*   min_sep       = (const int*)  d_in[4];
    const int*   n_donH        = (const int*)  d_in[5];
    const int*   n_acc         = (const int*)  d_in[6];
    const int*   donH_inds     = (const int*)  d_in[7];
    const int*   acc_inds      = (const int*)  d_in[8];
    const int*   donor_type    = (const int*)  d_in[9];
    const int*   acceptor_type = (const int*)  d_in[10];
    const int*   acceptor_hyb  = (const int*)  d_in[11];
    const float* pair_params   = (const float*)d_in[12];
    const float* pair_poly     = (const float*)d_in[13];
    const float* gp            = (const float*)d_in[14];
    float*       out           = (float*)d_out;
    float4*      ws            = (float4*)d_ws;

    const int pre = (ws_size >= WS_NEEDED) ? 1 : 0;
    if (pre) {
        pre_kernel<<<(NP * ACC_SLOTS + 255) / 256, 256, 0, stream>>>(
            coords, coord_off, block_type, n_donH, n_acc, donH_inds, acc_inds,
            donor_type, acceptor_type, acceptor_hyb, ws, out);
    } else {
        zero_out_kernel<<<1, 64, 0, stream>>>(out);
    }

    hbond_kernel<<<NP * NWG_PER_POSE, 256, 0, stream>>>(
        coords, coord_off, block_type, min_sep,
        n_donH, n_acc, donH_inds, acc_inds,
        donor_type, acceptor_type, acceptor_hyb,
        pair_params, pair_poly, gp, ws, pre, out);
}